// Round 15
// baseline (1002.466 us; speedup 1.0000x reference)
//
#include <hip/hip_runtime.h>

typedef _Float16 f16;
typedef _Float16 f16x2 __attribute__((ext_vector_type(2)));
typedef _Float16 f16x4 __attribute__((ext_vector_type(4)));
typedef _Float16 f16x8 __attribute__((ext_vector_type(8)));
typedef float    f32x4 __attribute__((ext_vector_type(4)));
typedef int      intx4 __attribute__((ext_vector_type(4)));

// ---------------- small helper kernels ----------------

__global__ void cvt_f32_to_f16(const float* __restrict__ in, f16* __restrict__ out, int n) {
  int i = (blockIdx.x * blockDim.x + threadIdx.x) * 4;
  if (i + 3 < n) {
    float4 v = *(const float4*)(in + i);
    f16x4 h; h[0] = (f16)v.x; h[1] = (f16)v.y; h[2] = (f16)v.z; h[3] = (f16)v.w;
    *(f16x4*)(out + i) = h;
  }
}

__global__ void bias_comb_kernel(const float* __restrict__ a, const float* __restrict__ b,
                                 float* __restrict__ o, int n) {
  int i = blockIdx.x * blockDim.x + threadIdx.x;
  if (i < n) o[i] = a[i] + b[i];
}

__global__ void zero_u32_kernel(unsigned* p) { *p = 0u; }

// abs-max of W into *out (uint-ordered float bits; all values >= 0)
__global__ void wabsmax_kernel(const float* __restrict__ in, int n, unsigned* out) {
  float m = 0.f;
  for (int i = blockIdx.x * blockDim.x + threadIdx.x; i < n; i += gridDim.x * blockDim.x)
    m = fmaxf(m, fabsf(in[i]));
#pragma unroll
  for (int off = 32; off >= 1; off >>= 1)
    m = fmaxf(m, __shfl_xor(m, off));
  if ((threadIdx.x & 63) == 0) atomicMax(out, __float_as_uint(m));
}

// quantize W to i8 with scale s = wmax/127
__global__ void quant_w_kernel(const float* __restrict__ W, signed char* __restrict__ out,
                               const unsigned* __restrict__ wmax, int n) {
  float mx = __uint_as_float(*wmax);
  float inv = mx > 0.f ? 127.f / mx : 0.f;
  int i = (blockIdx.x * blockDim.x + threadIdx.x) * 4;
  if (i + 3 < n) {
    float4 v = *(const float4*)(W + i);
    int q0 = (int)__builtin_rintf(v.x * inv);
    int q1 = (int)__builtin_rintf(v.y * inv);
    int q2 = (int)__builtin_rintf(v.z * inv);
    int q3 = (int)__builtin_rintf(v.w * inv);
    unsigned p = (unsigned)(q0 & 255) | ((unsigned)(q1 & 255) << 8) |
                 ((unsigned)(q2 & 255) << 16) | ((unsigned)(q3 & 255) << 24);
    *(unsigned*)(out + i) = p;
  }
}

// ---------------- GEMM: C[M,N] = A[M,K] * B[N,K]^T + bias[N] ----------------

#define BM 128
#define BN 128
#define BKT 32
#define LDK 40  // padded leading dim (f16 elems) to dodge bank conflicts

template <bool A_IS_F32>
__global__ __launch_bounds__(256, 2) void gemm_f16_kernel(
    const void* __restrict__ Aptr,    // [M][K]
    const f16* __restrict__ B,        // [N][K]
    const float* __restrict__ bias,   // [N]
    float* __restrict__ C,            // [M][N]
    int M, int N, int K) {
  __shared__ f16 As[BM][LDK];
  __shared__ f16 Bs[BN][LDK];

  const int tid = threadIdx.x;
  const int bm = blockIdx.y, bn = blockIdx.x;
  const int wave = tid >> 6, lane = tid & 63;
  const int wm = wave >> 1, wn = wave & 1;

  f32x4 acc[4][4] = {};

  for (int k0 = 0; k0 < K; k0 += BKT) {
#pragma unroll
    for (int it = 0; it < 2; ++it) {
      int idx = tid + it * 256;          // 0..511
      int row = idx >> 2;                // 0..127
      int kc  = (idx & 3) << 3;          // 0,8,16,24
      if (A_IS_F32) {
        const float* Af = (const float*)Aptr + (size_t)(bm * BM + row) * K + k0 + kc;
        float4 v0 = *(const float4*)Af;
        float4 v1 = *(const float4*)(Af + 4);
        f16x8 h;
        h[0] = (f16)v0.x; h[1] = (f16)v0.y; h[2] = (f16)v0.z; h[3] = (f16)v0.w;
        h[4] = (f16)v1.x; h[5] = (f16)v1.y; h[6] = (f16)v1.z; h[7] = (f16)v1.w;
        *(f16x8*)&As[row][kc] = h;
      } else {
        const f16* Ah = (const f16*)Aptr + (size_t)(bm * BM + row) * K + k0 + kc;
        *(f16x8*)&As[row][kc] = *(const f16x8*)Ah;
      }
      const f16* Bh = B + (size_t)(bn * BN + row) * K + k0 + kc;
      *(f16x8*)&Bs[row][kc] = *(const f16x8*)Bh;
    }
    __syncthreads();

    const int fr = lane & 15;
    const int fk = (lane >> 4) << 3;  // 0,8,16,24
    f16x8 af[4], bf[4];
#pragma unroll
    for (int i = 0; i < 4; ++i) af[i] = *(const f16x8*)&As[wm * 64 + i * 16 + fr][fk];
#pragma unroll
    for (int j = 0; j < 4; ++j) bf[j] = *(const f16x8*)&Bs[wn * 64 + j * 16 + fr][fk];
#pragma unroll
    for (int i = 0; i < 4; ++i)
#pragma unroll
      for (int j = 0; j < 4; ++j)
        acc[i][j] = __builtin_amdgcn_mfma_f32_16x16x32_f16(af[i], bf[j], acc[i][j], 0, 0, 0);
    __syncthreads();
  }

  const int fr = lane & 15;
  const int fq = lane >> 4;
#pragma unroll
  for (int i = 0; i < 4; ++i)
#pragma unroll
    for (int j = 0; j < 4; ++j)
#pragma unroll
      for (int r = 0; r < 4; ++r) {
        int row = bm * BM + wm * 64 + i * 16 + fq * 4 + r;
        int col = bn * BN + wn * 64 + j * 16 + fr;
        C[(size_t)row * N + col] = acc[i][j][r] + bias[col];
      }
}

// ---------------- recurrent scan (i8 MFMA v4: 4 waves, 8 tiles/wave) --------
// r14 counters: step 1810 cyc; LDS pipe = 64 ds_read_b128 x 12 = 770 cyc was
// the critical resource (each of 8 waves redundantly broadcasts all of h).
// r15: 256 threads = 4 waves (1/SIMD). Wave w owns 128 outputs
// j = 128w + 16*nt + col, nt=0..7. LDS A-reads halve to 32/step; MFMA issue
// per SIMD unchanged (64 x 4 = 256 cyc). B = 64 intx4/lane in AGPRs via asm
// "a" (256 AGPRs; 1 wave/SIMD -> 512-reg unified budget). 8 accumulator
// chains, dep distance 8. Epilogue: 2 outputs/lane (cndmask select), fully
// coalesced. Hazard fence identical to r14 (all accumulators pinned).
// Integer math exact and identical to r7/r12/r14 -> absmax 0.0078125.

#define RT 256

#define MFMA(d, a, b) \
  asm("v_mfma_i32_16x16x64_i8 %0, %1, %2, %0" : "+v"(d) : "v"(a), "a"(b))

#define KSTEP(s) {                 \
    MFMA(d0, A##s, B##s##_0);      \
    MFMA(d1, A##s, B##s##_1);      \
    MFMA(d2, A##s, B##s##_2);      \
    MFMA(d3, A##s, B##s##_3);      \
    MFMA(d4, A##s, B##s##_4);      \
    MFMA(d5, A##s, B##s##_5);      \
    MFMA(d6, A##s, B##s##_6);      \
    MFMA(d7, A##s, B##s##_7); }

#define BLD(s, nt) (*(const intx4*)(Whq + (size_t)(jb + (nt) * 16) * 512 + (s) * 64 + qoff))

__global__ __launch_bounds__(RT, 1) void rnn_scan_kernel(
    const signed char* __restrict__ Whq,  // [512][512] i8 (row j = W_hh row j)
    const unsigned* __restrict__ wmax,    // scale source
    const float* __restrict__ h0,         // [B][512] f32
    const float* __restrict__ xp,         // [B][T][512] f32 (pre-act incl. biases)
    f16* __restrict__ hs,                 // [B][T][512] f16 (out, for y-GEMM)
    float* __restrict__ hn,               // [B][512] f32 (out)
    int T) {
  __shared__ __align__(64) signed char hbuf[2][512];   // 1 KB
  const int tid  = threadIdx.x;
  const int lane = tid & 63;
  const int w    = tid >> 6;
  const int b    = blockIdx.x;
  const int g    = lane >> 4;           // k-quarter / tile-select group 0..3
  const int jb   = w * 128 + (lane & 15);
  const int j1   = jb + g * 16;         // this lane's output 1 (tiles 0..3)
  const int j2   = j1 + 64;             // this lane's output 2 (tiles 4..7)
  const int qoff = g << 4;              // k-quarter byte offset within 64

  const float qs = __uint_as_float(*wmax) * (1.0f / 16129.0f);

  // ---- load W B-fragments: 8 tiles x 8 k-steps (AGPR-resident via asm "a") ----
  intx4 B0_0=BLD(0,0), B0_1=BLD(0,1), B0_2=BLD(0,2), B0_3=BLD(0,3),
        B0_4=BLD(0,4), B0_5=BLD(0,5), B0_6=BLD(0,6), B0_7=BLD(0,7);
  intx4 B1_0=BLD(1,0), B1_1=BLD(1,1), B1_2=BLD(1,2), B1_3=BLD(1,3),
        B1_4=BLD(1,4), B1_5=BLD(1,5), B1_6=BLD(1,6), B1_7=BLD(1,7);
  intx4 B2_0=BLD(2,0), B2_1=BLD(2,1), B2_2=BLD(2,2), B2_3=BLD(2,3),
        B2_4=BLD(2,4), B2_5=BLD(2,5), B2_6=BLD(2,6), B2_7=BLD(2,7);
  intx4 B3_0=BLD(3,0), B3_1=BLD(3,1), B3_2=BLD(3,2), B3_3=BLD(3,3),
        B3_4=BLD(3,4), B3_5=BLD(3,5), B3_6=BLD(3,6), B3_7=BLD(3,7);
  intx4 B4_0=BLD(4,0), B4_1=BLD(4,1), B4_2=BLD(4,2), B4_3=BLD(4,3),
        B4_4=BLD(4,4), B4_5=BLD(4,5), B4_6=BLD(4,6), B4_7=BLD(4,7);
  intx4 B5_0=BLD(5,0), B5_1=BLD(5,1), B5_2=BLD(5,2), B5_3=BLD(5,3),
        B5_4=BLD(5,4), B5_5=BLD(5,5), B5_6=BLD(5,6), B5_7=BLD(5,7);
  intx4 B6_0=BLD(6,0), B6_1=BLD(6,1), B6_2=BLD(6,2), B6_3=BLD(6,3),
        B6_4=BLD(6,4), B6_5=BLD(6,5), B6_6=BLD(6,6), B6_7=BLD(6,7);
  intx4 B7_0=BLD(7,0), B7_1=BLD(7,1), B7_2=BLD(7,2), B7_3=BLD(7,3),
        B7_4=BLD(7,4), B7_5=BLD(7,5), B7_6=BLD(7,6), B7_7=BLD(7,7);

  {
    float hv = h0[(size_t)b * 512 + tid];
    hv = fminf(1.f, fmaxf(-1.f, hv));
    hbuf[0][tid] = (signed char)(int)__builtin_rintf(127.f * hv);
    float hv2 = h0[(size_t)b * 512 + tid + 256];
    hv2 = fminf(1.f, fmaxf(-1.f, hv2));
    hbuf[0][tid + 256] = (signed char)(int)__builtin_rintf(127.f * hv2);
  }
  __syncthreads();

  const float* xpb1 = xp + (size_t)b * T * 512 + j1;
  const float* xpb2 = xpb1 + 64;
  f16* hsb1 = hs + (size_t)b * T * 512 + j1;
  f16* hsb2 = hsb1 + 64;

  int cur = 0;
  float hl1 = 0.f, hl2 = 0.f;
  float xv1 = xpb1[0], xv2 = xpb2[0];

  for (int t = 0; t < T; ++t) {
    int tn = t + 1 < T ? t + 1 : t;
    float xn1 = xpb1[(size_t)tn * 512];   // prefetch next step's xp (coalesced)
    float xn2 = xpb2[(size_t)tn * 512];

    // ---- hoist all 8 A-fragment loads (latency overlaps MFMA issue) ----
    const intx4* ap = (const intx4*)(&hbuf[cur][0] + qoff);
    intx4 A0 = ap[0],  A1 = ap[4],  A2 = ap[8],  A3 = ap[12],
          A4 = ap[16], A5 = ap[20], A6 = ap[24], A7 = ap[28];

    intx4 d0 = {0,0,0,0}, d1 = {0,0,0,0}, d2 = {0,0,0,0}, d3 = {0,0,0,0},
          d4 = {0,0,0,0}, d5 = {0,0,0,0}, d6 = {0,0,0,0}, d7 = {0,0,0,0};
    // 8 accumulator chains; same-accumulator dep distance = 8 MFMAs
    KSTEP(0) KSTEP(1) KSTEP(2) KSTEP(3)
    KSTEP(4) KSTEP(5) KSTEP(6) KSTEP(7)
    // nothing may migrate across this point
    __builtin_amdgcn_sched_barrier(0);
    // XDL RAW hazard cushion: pin ALL EIGHT accumulators (r14-proven pattern)
    asm volatile("s_nop 7\ns_nop 7\ns_nop 7"
                 : "+v"(d0), "+v"(d1), "+v"(d2), "+v"(d3),
                   "+v"(d4), "+v"(d5), "+v"(d6), "+v"(d7));

    // ---- every lane: two outputs. All 16 D rows identical -> reg 0 valid. ----
    int s0 = d0[0], s1 = d1[0], s2 = d2[0], s3 = d3[0];
    int s4 = d4[0], s5 = d5[0], s6 = d6[0], s7 = d7[0];
    int t01 = (g & 1) ? s1 : s0;
    int t23 = (g & 1) ? s3 : s2;
    int slo = (g & 2) ? t23 : t01;
    int t45 = (g & 1) ? s5 : s4;
    int t67 = (g & 1) ? s7 : s6;
    int shi = (g & 2) ? t67 : t45;

    float y1 = (float)slo * qs + xv1;
    float y2 = (float)shi * qs + xv2;
    // tanh(x) = 1 - 2/(exp(2x)+1); branch-free
    float e1 = __expf(2.f * y1), e2 = __expf(2.f * y2);
    float h1 = 1.f - 2.f * __builtin_amdgcn_rcpf(e1 + 1.f);
    float h2 = 1.f - 2.f * __builtin_amdgcn_rcpf(e2 + 1.f);
    hl1 = h1; hl2 = h2;
    size_t ho = (size_t)t * 512;
    hsb1[ho] = (f16)h1;                  // 128B/wave contiguous
    hsb2[ho] = (f16)h2;
    signed char* hbw = hbuf[cur ^ 1];
    hbw[j1] = (signed char)(int)__builtin_rintf(127.f * h1);
    hbw[j2] = (signed char)(int)__builtin_rintf(127.f * h2);
    __syncthreads();
    cur ^= 1;
    xv1 = xn1; xv2 = xn2;
  }
  hn[(size_t)b * 512 + j1] = hl1;
  hn[(size_t)b * 512 + j2] = hl2;
}

// ---------------- launch ----------------

extern "C" void kernel_launch(void* const* d_in, const int* in_sizes, int n_in,
                              void* d_out, int out_size, void* d_ws, size_t ws_size,
                              hipStream_t stream) {
  const float* x    = (const float*)d_in[0];
  const float* h0   = (const float*)d_in[1];
  const float* W_xh = (const float*)d_in[2];
  const float* b_xh = (const float*)d_in[3];
  const float* W_hh = (const float*)d_in[4];
  const float* b_hh = (const float*)d_in[5];
  const float* W_hy = (const float*)d_in[6];
  const float* b_hy = (const float*)d_in[7];

  const int H = 512;
  const int B = in_sizes[1] / H;            // 64
  const int T = in_sizes[0] / (B * H);      // 1024
  const int M = B * T;                      // 65536

  float* out = (float*)d_out;               // y [M][512] then h_n [B][512]
  float* xpb = out;                         // reuse y region as xp scratch
  float* hn  = out + (size_t)M * H;

  char* w = (char*)d_ws;
  f16*         hsb    = (f16*)w;                              // M*H*2 bytes
  f16*         Wxh_h  = (f16*)(w + (size_t)M * H * 2);        // H*H f16
  f16*         Why_h  = Wxh_h + H * H;                        // H*H f16
  signed char* Whq    = (signed char*)(Why_h + H * H);        // H*H i8
  float*       biasc  = (float*)(Whq + H * H);                // H f32
  unsigned*    wmax   = (unsigned*)(biasc + H);               // 1 u32

  const int WN = H * H;  // 262144
  cvt_f32_to_f16<<<WN / 1024, 256, 0, stream>>>(W_xh, Wxh_h, WN);
  cvt_f32_to_f16<<<WN / 1024, 256, 0, stream>>>(W_hy, Why_h, WN);
  bias_comb_kernel<<<2, 256, 0, stream>>>(b_xh, b_hh, biasc, H);

  // quantize W_hh to i8 with measured absmax scale
  zero_u32_kernel<<<1, 1, 0, stream>>>(wmax);
  wabsmax_kernel<<<64, 256, 0, stream>>>(W_hh, WN, wmax);
  quant_w_kernel<<<WN / 1024, 256, 0, stream>>>(W_hh, Whq, wmax, WN);

  // xp = x @ W_xh^T + (b_xh + b_hh)   (written into d_out)
  gemm_f16_kernel<true><<<dim3(H / BN, M / BM), 256, 0, stream>>>(
      x, Wxh_h, biasc, xpb, M, H, H);

  // sequential scan; writes hs (f16, ws) and h_n (f32, d_out tail)
  rnn_scan_kernel<<<B, RT, 0, stream>>>(Whq, wmax, h0, xpb, hsb, hn, T);

  // y = hs @ W_hy^T + b_hy   (overwrites xp region of d_out)
  gemm_f16_kernel<false><<<dim3(H / BN, M / BM), 256, 0, stream>>>(
      hsb, Why_h, b_hy, out, M, H, H);
}